// Round 8
// baseline (23.893 us; speedup 1.0000x reference)
//
#include <hip/hip_runtime.h>

#define NSTROKES 64
#define NSAMP    50
#define CANVAS   512
#define HW       (CANVAS * CANVAS)
#define TPB      512   // 1 px/thread, one 512-px row per block, 8 waves
#define SPW      (NSTROKES / 8)        // 8 strokes per wave (stage A)
#define LSTRIDE  52                    // float2 slots per stroke list

// ---------------------------------------------------------------------------
// Single fused kernel: one block per canvas row, all 64 strokes.
//  stage A: ballot compaction of row-band samples into LDS lists (sentinel-
//           padded to even length); per-stroke cull float4 (xlo,xhi,w,cnt).
//  stage B: stroke s <-> lane s (64 strokes == 64 lanes): one LDS read +
//           one __ballot builds the wave's 64-bit live mask; iterate set
//           bits in ascending order (preserves composite order); blend;
//           write final color (white canvas: c = A + B) straight to out.
// ---------------------------------------------------------------------------
__global__ __launch_bounds__(TPB) void raster_fused_kernel(
    const float* __restrict__ strokes,   // (64,4,2)
    const float* __restrict__ widths,    // (64,)
    const float* __restrict__ colors,    // (64,3)
    float* __restrict__ out)             // (1,3,512,512)
{
    __shared__ __align__(16) float2 slist[NSTROKES * LSTRIDE];  // ~26.6 KB
    __shared__ float4 scull[NSTROKES];   // xmin-cut, xmax+cut, w, cnt
    __shared__ float4 scol [NSTROKES];   // r,g,b,pad

    const int tid  = threadIdx.x;
    const int wave = tid >> 6;
    const int lane = tid & 63;
    const int y    = blockIdx.x;
    const float fy = (float)y;

    // ---- stage A: compaction, SPW strokes per wave, lane = sample index
    #pragma unroll
    for (int i = 0; i < SPW; ++i) {
        const int s = wave * SPW + i;        // stroke id 0..63

        float4 a = ((const float4*)strokes)[s * 2];       // p0x,p0y,p1x,p1y
        float4 b = ((const float4*)strokes)[s * 2 + 1];   // p2x,p2y,p3x,p3y
        const float S = (float)CANVAS;
        float c0x = a.x * S;
        float c1x = 3.0f * (a.z - a.x) * S;
        float c2x = 3.0f * (b.x - 2.0f * a.z + a.x) * S;
        float c3x = (b.z - 3.0f * b.x + 3.0f * a.z - a.x) * S;
        float c0y = a.y * S;
        float c1y = 3.0f * (a.w - a.y) * S;
        float c2y = 3.0f * (b.y - 2.0f * a.w + a.y) * S;
        float c3y = (b.w - 3.0f * b.y + 3.0f * a.w - a.y) * S;

        float w   = widths[s];
        float cut = w + 10.0f;               // alpha <= sigmoid(-20) ~ 2e-9 beyond

        float t  = (float)lane * (1.0f / (float)(NSAMP - 1));
        float px = fmaf(fmaf(fmaf(c3x, t, c2x), t, c1x), t, c0x);
        float py = fmaf(fmaf(fmaf(c3y, t, c2y), t, c1y), t, c0y);

        bool keep = (lane < NSAMP) && (fabsf(py - fy) <= cut);
        unsigned long long mask = __ballot(keep);
        int idx = __popcll(mask & ((1ull << lane) - 1ull));
        if (keep) slist[s * LSTRIDE + idx] = make_float2(px, py);
        // lane 63 never keeps -> its idx == cnt: free sentinel (kills remainder)
        if (lane == 63) slist[s * LSTRIDE + idx] = make_float2(1e15f, 1e15f);

        if (mask) {
            float vmn = keep ? px : 1e30f;
            float vmx = keep ? px : -1e30f;
            #pragma unroll
            for (int off = 32; off; off >>= 1) {
                vmn = fminf(vmn, __shfl_xor(vmn, off));
                vmx = fmaxf(vmx, __shfl_xor(vmx, off));
            }
            if (lane == 0) {
                scull[s] = make_float4(vmn - cut, vmx + cut, w,
                                       (float)__popcll(mask));
                scol [s] = make_float4(colors[3*s], colors[3*s+1],
                                       colors[3*s+2], 0.0f);
            }
        } else if (lane == 0) {
            scull[s] = make_float4(0.0f, 0.0f, w, 0.0f);   // cnt=0 -> culled
        }
    }
    __syncthreads();

    // ---- stage B: lane s tests stroke s; one ballot = 64-stroke live mask
    const float fx      = (float)tid;
    const float span_lo = (float)(wave << 6);
    const float span_hi = span_lo + 63.0f;

    float4 cbl = scull[lane];
    bool alive = (cbl.w > 0.0f) && (cbl.x <= span_hi) && (cbl.y >= span_lo);
    unsigned long long live = __ballot(alive);

    float A = 1.0f, br = 0.0f, bg = 0.0f, bb = 0.0f;

    while (live) {
        const int s = __ffsll(live) - 1;     // ascending s: composite order
        live &= live - 1ull;

        float4 cb  = scull[s];               // broadcast LDS read
        float4 col = scol [s];
        const int   kc = (int)cb.w;
        const float w  = cb.z;

        float m = 1e30f;
        const float2* L = slist + s * LSTRIDE;
        for (int j = 0; j < kc; j += 2) {          // sentinel pads odd kc
            float4 q = *(const float4*)(L + j);    // 2 samples, broadcast
            float dy0 = fy - q.y;
            float dy1 = fy - q.w;
            float da  = fx - q.x;
            float db  = fx - q.z;
            m = fminf(fminf(fmaf(da, da, dy0 * dy0),
                            fmaf(db, db, dy1 * dy1)), m);
        }

        float al = __builtin_amdgcn_rcpf(1.0f + __expf(2.0f * (sqrtf(m) - w)));
        A  *= (1.0f - al);
        br  = fmaf(al, col.x - br, br);
        bg  = fmaf(al, col.y - bg, bg);
        bb  = fmaf(al, col.z - bb, bb);
    }

    // white canvas: c = A*1 + B
    const int base = y * CANVAS + tid;
    out[0*HW + base] = A + br;
    out[1*HW + base] = A + bg;
    out[2*HW + base] = A + bb;
}

extern "C" void kernel_launch(void* const* d_in, const int* in_sizes, int n_in,
                              void* d_out, int out_size, void* d_ws, size_t ws_size,
                              hipStream_t stream) {
    const float* strokes = (const float*)d_in[0];
    const float* widths  = (const float*)d_in[1];
    const float* colors  = (const float*)d_in[2];
    float* out = (float*)d_out;

    raster_fused_kernel<<<dim3(CANVAS), dim3(TPB), 0, stream>>>(
        strokes, widths, colors, out);
}

// Round 9
// 19.050 us; speedup vs baseline: 1.2542x; 1.2542x over previous
//
#include <hip/hip_runtime.h>

#define NSTROKES 64
#define NSAMP    50
#define CANVAS   512
#define HW       (CANVAS * CANVAS)
#define TPB      1024                  // 512 px  x  2 stroke-groups, 16 waves
#define SPW      (NSTROKES / 16)       // 4 strokes per wave (stage A)
#define LSTRIDE  64                    // float2 slots per stroke list (pow2, fits 50+14 sentinels)

// ---------------------------------------------------------------------------
// Single kernel, one block per canvas row.
//  threads: tid = px + 512*grp; grp 0 composites strokes 0..31, grp 1 strokes
//  32..63 (independent affine maps c -> A*c + B), folded in LDS at the end:
//  c = A1*(A0*white + B0) + B1.  512 blocks x 16 waves = 8192 waves.
//  stage A: ballot compaction of row-band samples into LDS lists; lanes
//           50..63 (never keep) write sentinels at slots kc..kc+13 -> lists
//           padded to a multiple of 4 for the unrolled-by-4 stage-B loop.
//  stage B: lane l tests stroke grp*32+(l&31) against the wave's 64-px span;
//           low 32 ballot bits = live mask; iterate set bits ascending.
// ---------------------------------------------------------------------------
__global__ __launch_bounds__(TPB, 8) void raster_fused_kernel(
    const float* __restrict__ strokes,   // (64,4,2)
    const float* __restrict__ widths,    // (64,)
    const float* __restrict__ colors,    // (64,3)
    float* __restrict__ out)             // (1,3,512,512)
{
    __shared__ __align__(16) float2 slist[NSTROKES * LSTRIDE];  // 32 KB
    __shared__ float4 scull[NSTROKES];   // xmin-cut, xmax+cut, w, cnt
    __shared__ float4 scol [NSTROKES];   // r,g,b,pad

    const int tid  = threadIdx.x;
    const int wave = tid >> 6;
    const int lane = tid & 63;
    const int px   = tid & 511;
    const int grp  = tid >> 9;           // 0: strokes 0-31, 1: strokes 32-63
    const int y    = blockIdx.x;
    const float fy = (float)y;

    // ---- stage A: compaction, SPW strokes per wave, lane = sample index
    #pragma unroll
    for (int i = 0; i < SPW; ++i) {
        const int s = wave * SPW + i;        // stroke id 0..63

        float4 a = ((const float4*)strokes)[s * 2];       // p0x,p0y,p1x,p1y
        float4 b = ((const float4*)strokes)[s * 2 + 1];   // p2x,p2y,p3x,p3y
        const float S = (float)CANVAS;
        float c0x = a.x * S;
        float c1x = 3.0f * (a.z - a.x) * S;
        float c2x = 3.0f * (b.x - 2.0f * a.z + a.x) * S;
        float c3x = (b.z - 3.0f * b.x + 3.0f * a.z - a.x) * S;
        float c0y = a.y * S;
        float c1y = 3.0f * (a.w - a.y) * S;
        float c2y = 3.0f * (b.y - 2.0f * a.w + a.y) * S;
        float c3y = (b.w - 3.0f * b.y + 3.0f * a.w - a.y) * S;

        float w   = widths[s];
        float cut = w + 10.0f;               // alpha <= sigmoid(-20) ~ 2e-9 beyond

        float t  = (float)lane * (1.0f / (float)(NSAMP - 1));
        float px_ = fmaf(fmaf(fmaf(c3x, t, c2x), t, c1x), t, c0x);
        float py_ = fmaf(fmaf(fmaf(c3y, t, c2y), t, c1y), t, c0y);

        bool keep = (lane < NSAMP) && (fabsf(py_ - fy) <= cut);
        unsigned long long mask = __ballot(keep);
        int idx = __popcll(mask & ((1ull << lane) - 1ull));
        if (keep) {
            slist[s * LSTRIDE + idx] = make_float2(px_, py_);
        } else if (lane >= NSAMP) {
            // lanes 50..63: idx == kc for all -> consecutive sentinel slots
            slist[s * LSTRIDE + idx + (lane - NSAMP)] = make_float2(1e15f, 1e15f);
        }

        if (mask) {
            float vmn = keep ? px_ : 1e30f;
            float vmx = keep ? px_ : -1e30f;
            #pragma unroll
            for (int off = 32; off; off >>= 1) {
                vmn = fminf(vmn, __shfl_xor(vmn, off));
                vmx = fmaxf(vmx, __shfl_xor(vmx, off));
            }
            if (lane == 0) {
                scull[s] = make_float4(vmn - cut, vmx + cut, w,
                                       (float)__popcll(mask));
                scol [s] = make_float4(colors[3*s], colors[3*s+1],
                                       colors[3*s+2], 0.0f);
            }
        } else if (lane == 0) {
            scull[s] = make_float4(0.0f, 0.0f, w, 0.0f);   // cnt=0 -> culled
        }
    }
    __syncthreads();

    // ---- stage B: lane l tests stroke grp*32+(l&31); low 32 ballot bits
    const float fx      = (float)px;
    const float span_lo = (float)((wave & 7) << 6);
    const float span_hi = span_lo + 63.0f;
    const int   sbase   = grp << 5;

    float4 cbl = scull[sbase + (lane & 31)];
    bool alive = (cbl.w > 0.0f) && (cbl.x <= span_hi) && (cbl.y >= span_lo);
    unsigned int live = (unsigned int)__ballot(alive);   // low 32 == high 32

    float A = 1.0f, br = 0.0f, bg = 0.0f, bb = 0.0f;

    while (live) {
        const int sl = __ffs(live) - 1;      // ascending: composite order
        live &= live - 1u;
        const int s = sbase + sl;

        float4 cb  = scull[s];               // broadcast LDS read
        float4 col = scol [s];
        const int   kc = (int)cb.w;
        const float w  = cb.z;

        float m = 1e30f;
        const float4* L4 = (const float4*)(slist + s * LSTRIDE);
        for (int j = 0; j < kc; j += 4) {          // sentinel-padded to 4
            float4 q0 = L4[(j >> 1)];              // samples j, j+1
            float4 q1 = L4[(j >> 1) + 1];          // samples j+2, j+3
            float dy0 = fy - q0.y, dy1 = fy - q0.w;
            float dy2 = fy - q1.y, dy3 = fy - q1.w;
            float d0  = fx - q0.x, d1  = fx - q0.z;
            float d2  = fx - q1.x, d3  = fx - q1.z;
            float m01 = fminf(fmaf(d0, d0, dy0 * dy0), fmaf(d1, d1, dy1 * dy1));
            float m23 = fminf(fmaf(d2, d2, dy2 * dy2), fmaf(d3, d3, dy3 * dy3));
            m = fminf(fminf(m01, m23), m);
        }

        float al = __builtin_amdgcn_rcpf(1.0f + __expf(2.0f * (sqrtf(m) - w)));
        A  *= (1.0f - al);
        br  = fmaf(al, col.x - br, br);
        bg  = fmaf(al, col.y - bg, bg);
        bb  = fmaf(al, col.z - bb, bb);
    }

    // ---- combine: g0 publishes (A,B) via LDS (slist is dead), g1 folds
    __syncthreads();
    float4* xfer = (float4*)slist;           // 512 x float4 = 8 KB
    if (grp == 0) {
        xfer[px] = make_float4(A, br, bg, bb);
    }
    __syncthreads();
    if (grp == 1) {
        float4 g0 = xfer[px];
        // white canvas: c0 = A0*1 + B0; then c = A1*c0 + B1
        float cr = fmaf(A, g0.x + g0.y, br);
        float cg = fmaf(A, g0.x + g0.z, bg);
        float cb = fmaf(A, g0.x + g0.w, bb);
        const int base = y * CANVAS + px;
        out[0*HW + base] = cr;
        out[1*HW + base] = cg;
        out[2*HW + base] = cb;
    }
}

extern "C" void kernel_launch(void* const* d_in, const int* in_sizes, int n_in,
                              void* d_out, int out_size, void* d_ws, size_t ws_size,
                              hipStream_t stream) {
    const float* strokes = (const float*)d_in[0];
    const float* widths  = (const float*)d_in[1];
    const float* colors  = (const float*)d_in[2];
    float* out = (float*)d_out;

    raster_fused_kernel<<<dim3(CANVAS), dim3(TPB), 0, stream>>>(
        strokes, widths, colors, out);
}

// Round 10
// 18.082 us; speedup vs baseline: 1.3214x; 1.0535x over previous
//
#include <hip/hip_runtime.h>

#define NSTROKES 64
#define NSAMP    50
#define CANVAS   512
#define HW       (CANVAS * CANVAS)
#define TPB      1024                  // 512 px  x  2 stroke-groups, 16 waves
#define SPW      (NSTROKES / 16)       // 4 strokes per wave (stage A)
#define LSTRIDE  64                    // float2 slots per stroke list

// ---------------------------------------------------------------------------
// Single kernel, one block per canvas row.
//  tid = px + 512*grp; grp 0 composites strokes 0..31, grp 1 strokes 32..63
//  (independent affine maps c -> A*c + B), folded in LDS at the end:
//  c = A1*(A0*white + B0) + B1.  512 blocks x 16 waves = 8192 waves.
//  stage A: ballot compaction of row-band samples into LDS lists; lanes
//           50..63 write sentinels at slots kc..kc+13 (covers the 4-wide
//           loop's over-read).
//  stage B: lane l tests stroke grp*32+(l&31) -> 32-bit live mask. NEW:
//           process TWO live strokes per iteration with interleaved,
//           independent LDS-read chains (2x memory-level parallelism on the
//           dominant latency chain); blend order s0 then s1 (ascending)
//           preserves compositing semantics bit-exactly.
// ---------------------------------------------------------------------------
__global__ __launch_bounds__(TPB, 8) void raster_fused_kernel(
    const float* __restrict__ strokes,   // (64,4,2)
    const float* __restrict__ widths,    // (64,)
    const float* __restrict__ colors,    // (64,3)
    float* __restrict__ out)             // (1,3,512,512)
{
    __shared__ __align__(16) float2 slist[NSTROKES * LSTRIDE];  // 32 KB
    __shared__ float4 scull[NSTROKES];   // xmin-cut, xmax+cut, w, cnt
    __shared__ float4 scol [NSTROKES];   // r,g,b,pad

    const int tid  = threadIdx.x;
    const int wave = tid >> 6;
    const int lane = tid & 63;
    const int px   = tid & 511;
    const int grp  = tid >> 9;           // 0: strokes 0-31, 1: strokes 32-63
    const int y    = blockIdx.x;
    const float fy = (float)y;

    // ---- stage A: compaction, SPW strokes per wave, lane = sample index
    #pragma unroll
    for (int i = 0; i < SPW; ++i) {
        const int s = wave * SPW + i;        // stroke id 0..63

        float4 a = ((const float4*)strokes)[s * 2];       // p0x,p0y,p1x,p1y
        float4 b = ((const float4*)strokes)[s * 2 + 1];   // p2x,p2y,p3x,p3y
        const float S = (float)CANVAS;
        float c0x = a.x * S;
        float c1x = 3.0f * (a.z - a.x) * S;
        float c2x = 3.0f * (b.x - 2.0f * a.z + a.x) * S;
        float c3x = (b.z - 3.0f * b.x + 3.0f * a.z - a.x) * S;
        float c0y = a.y * S;
        float c1y = 3.0f * (a.w - a.y) * S;
        float c2y = 3.0f * (b.y - 2.0f * a.w + a.y) * S;
        float c3y = (b.w - 3.0f * b.y + 3.0f * a.w - a.y) * S;

        float w   = widths[s];
        float cut = w + 10.0f;               // alpha <= sigmoid(-20) ~ 2e-9 beyond

        float t   = (float)lane * (1.0f / (float)(NSAMP - 1));
        float px_ = fmaf(fmaf(fmaf(c3x, t, c2x), t, c1x), t, c0x);
        float py_ = fmaf(fmaf(fmaf(c3y, t, c2y), t, c1y), t, c0y);

        bool keep = (lane < NSAMP) && (fabsf(py_ - fy) <= cut);
        unsigned long long mask = __ballot(keep);
        int idx = __popcll(mask & ((1ull << lane) - 1ull));
        if (keep) {
            slist[s * LSTRIDE + idx] = make_float2(px_, py_);
        } else if (lane >= NSAMP) {
            // lanes 50..63: idx == kc for all -> consecutive sentinel slots
            slist[s * LSTRIDE + idx + (lane - NSAMP)] = make_float2(1e15f, 1e15f);
        }

        if (mask) {
            float vmn = keep ? px_ : 1e30f;
            float vmx = keep ? px_ : -1e30f;
            #pragma unroll
            for (int off = 32; off; off >>= 1) {
                vmn = fminf(vmn, __shfl_xor(vmn, off));
                vmx = fmaxf(vmx, __shfl_xor(vmx, off));
            }
            if (lane == 0) {
                scull[s] = make_float4(vmn - cut, vmx + cut, w,
                                       (float)__popcll(mask));
                scol [s] = make_float4(colors[3*s], colors[3*s+1],
                                       colors[3*s+2], 0.0f);
            }
        } else if (lane == 0) {
            scull[s] = make_float4(0.0f, 0.0f, w, 0.0f);   // cnt=0 -> culled
        }
    }
    __syncthreads();

    // ---- stage B: lane l tests stroke grp*32+(l&31); 32-bit live mask
    const float fx      = (float)px;
    const float span_lo = (float)((wave & 7) << 6);
    const float span_hi = span_lo + 63.0f;
    const int   sbase   = grp << 5;

    float4 cbl = scull[sbase + (lane & 31)];
    bool alive = (cbl.w > 0.0f) && (cbl.x <= span_hi) && (cbl.y >= span_lo);
    unsigned int live = (unsigned int)__ballot(alive);   // low 32 == high 32

    float A = 1.0f, br = 0.0f, bg = 0.0f, bb = 0.0f;

    while (live) {
        // pop up to TWO live strokes (ascending ids: composite order kept)
        const int s0 = sbase + (__ffs(live) - 1);
        live &= live - 1u;
        const bool has1 = (live != 0u);
        const int s1 = has1 ? (sbase + (__ffs(live) - 1)) : s0;
        if (has1) live &= live - 1u;

        // independent LDS reads issue back-to-back (2x MLP)
        float4 cb0  = scull[s0];
        float4 cb1  = scull[s1];
        float4 col0 = scol [s0];
        float4 col1 = scol [s1];
        const int   kc0 = (int)cb0.w;
        const int   kc1 = has1 ? (int)cb1.w : 0;
        const float w0  = cb0.z;
        const float w1  = cb1.z;

        float m0 = 1e30f, m1 = 1e30f;
        const float4* L0 = (const float4*)(slist + s0 * LSTRIDE);
        const float4* L1 = (const float4*)(slist + s1 * LSTRIDE);

        const int kmax = kc0 > kc1 ? kc0 : kc1;
        for (int j = 0; j < kmax; j += 4) {        // sentinel-padded to 4
            if (j < kc0) {                          // wave-uniform branch
                float4 q0 = L0[(j >> 1)];
                float4 q1 = L0[(j >> 1) + 1];
                float dy0 = fy - q0.y, dy1 = fy - q0.w;
                float dy2 = fy - q1.y, dy3 = fy - q1.w;
                float d0  = fx - q0.x, d1  = fx - q0.z;
                float d2  = fx - q1.x, d3  = fx - q1.z;
                float a01 = fminf(fmaf(d0, d0, dy0*dy0), fmaf(d1, d1, dy1*dy1));
                float a23 = fminf(fmaf(d2, d2, dy2*dy2), fmaf(d3, d3, dy3*dy3));
                m0 = fminf(fminf(a01, a23), m0);
            }
            if (j < kc1) {                          // wave-uniform branch
                float4 q0 = L1[(j >> 1)];
                float4 q1 = L1[(j >> 1) + 1];
                float dy0 = fy - q0.y, dy1 = fy - q0.w;
                float dy2 = fy - q1.y, dy3 = fy - q1.w;
                float d0  = fx - q0.x, d1  = fx - q0.z;
                float d2  = fx - q1.x, d3  = fx - q1.z;
                float a01 = fminf(fmaf(d0, d0, dy0*dy0), fmaf(d1, d1, dy1*dy1));
                float a23 = fminf(fmaf(d2, d2, dy2*dy2), fmaf(d3, d3, dy3*dy3));
                m1 = fminf(fminf(a01, a23), m1);
            }
        }

        // both alphas compute with ILP; blend strictly s0 then s1
        float al0 = __builtin_amdgcn_rcpf(1.0f + __expf(2.0f * (sqrtf(m0) - w0)));
        float al1 = __builtin_amdgcn_rcpf(1.0f + __expf(2.0f * (sqrtf(m1) - w1)));

        A  *= (1.0f - al0);
        br  = fmaf(al0, col0.x - br, br);
        bg  = fmaf(al0, col0.y - bg, bg);
        bb  = fmaf(al0, col0.z - bb, bb);
        if (has1) {
            A  *= (1.0f - al1);
            br  = fmaf(al1, col1.x - br, br);
            bg  = fmaf(al1, col1.y - bg, bg);
            bb  = fmaf(al1, col1.z - bb, bb);
        }
    }

    // ---- combine: g0 publishes (A,B) via LDS (slist is dead), g1 folds
    __syncthreads();
    float4* xfer = (float4*)slist;           // 512 x float4 = 8 KB
    if (grp == 0) {
        xfer[px] = make_float4(A, br, bg, bb);
    }
    __syncthreads();
    if (grp == 1) {
        float4 g0 = xfer[px];
        // white canvas: c0 = A0*1 + B0; then c = A1*c0 + B1
        float cr = fmaf(A, g0.x + g0.y, br);
        float cg = fmaf(A, g0.x + g0.z, bg);
        float cb = fmaf(A, g0.x + g0.w, bb);
        const int base = y * CANVAS + px;
        out[0*HW + base] = cr;
        out[1*HW + base] = cg;
        out[2*HW + base] = cb;
    }
}

extern "C" void kernel_launch(void* const* d_in, const int* in_sizes, int n_in,
                              void* d_out, int out_size, void* d_ws, size_t ws_size,
                              hipStream_t stream) {
    const float* strokes = (const float*)d_in[0];
    const float* widths  = (const float*)d_in[1];
    const float* colors  = (const float*)d_in[2];
    float* out = (float*)d_out;

    raster_fused_kernel<<<dim3(CANVAS), dim3(TPB), 0, stream>>>(
        strokes, widths, colors, out);
}